// Round 2
// baseline (465.788 us; speedup 1.0000x reference)
//
#include <hip/hip_runtime.h>

typedef unsigned short u16;
typedef __attribute__((ext_vector_type(8))) short bf16x8;
typedef __attribute__((ext_vector_type(4))) float f32x4;
typedef __attribute__((ext_vector_type(4))) unsigned short us4;

#define B_ 2
#define S_ 2048
#define D_ 1024
#define H_ 16
#define DH_ 64
#define M_ 4096 /* B*S */

__device__ __forceinline__ u16 f2bf(float f) {
  unsigned int u = __builtin_bit_cast(unsigned int, f);
  u += 0x7FFFu + ((u >> 16) & 1u);   // RNE
  return (u16)(u >> 16);
}

__device__ __forceinline__ void gload_lds16(const void* g, void* l) {
  __builtin_amdgcn_global_load_lds(
      (__attribute__((address_space(1))) void*)(g),
      (__attribute__((address_space(3))) void*)(l),
      16, 0, 0);
}

// ---------------- fp32 -> bf16 elementwise convert (vectorized) ----------------
__global__ __launch_bounds__(256) void cvt_kernel(const float* __restrict__ in,
                                                  u16* __restrict__ out, int n4) {
  int i = blockIdx.x * 256 + threadIdx.x;
  if (i >= n4) return;
  float4 v = ((const float4*)in)[i];
  us4 o;
  o[0] = f2bf(v.x); o[1] = f2bf(v.y); o[2] = f2bf(v.z); o[3] = f2bf(v.w);
  ((us4*)out)[i] = o;
}

// ---------------- W [K][N] fp32 -> Wt [N][K] bf16 (LDS tile transpose) ----------------
__global__ __launch_bounds__(256) void transpose_cvt_kernel(const float* __restrict__ W,
                                                            u16* __restrict__ Wt) {
  __shared__ float tile[32][33];
  int tx = threadIdx.x, ty = threadIdx.y;
  int x = blockIdx.x * 32 + tx;
  for (int j = 0; j < 32; j += 8)
    tile[ty + j][tx] = W[(size_t)(blockIdx.y * 32 + ty + j) * D_ + x];
  __syncthreads();
  int x2 = blockIdx.y * 32 + tx;
  for (int j = 0; j < 32; j += 8)
    Wt[(size_t)(blockIdx.x * 32 + ty + j) * D_ + x2] = f2bf(tile[tx][ty + j]);
}

// ---------------- GEMM: C[m][n] = sum_k A[m][k]*Bt[n][k] + bias[n] ----------------
template <int MODE>
__global__ __launch_bounds__(256) void gemm_bt(const u16* __restrict__ A,
                                               const u16* __restrict__ Bt,
                                               const float* __restrict__ bias,
                                               void* __restrict__ outp,
                                               int M, int N, int K) {
  __shared__ u16 As[128 * 32];
  __shared__ u16 Bs[128 * 32];
  int tid = threadIdx.x;
  int lane = tid & 63, wave = tid >> 6;
  int m0 = blockIdx.x * 128, n0 = blockIdx.y * 128;
  int wr = wave >> 1, wc = wave & 1;
  int fr = lane & 15, fk = (lane >> 4) * 8;

  f32x4 acc[4][4];
  const f32x4 vzero = {0.f, 0.f, 0.f, 0.f};
  for (int i = 0; i < 4; ++i)
    for (int j = 0; j < 4; ++j) acc[i][j] = vzero;

  for (int k0 = 0; k0 < K; k0 += 32) {
    if (k0) __syncthreads();
    for (int i = 0; i < 2; ++i) {
      int wofs = ((i * 4 + wave) << 10);
      int ofs = wofs + lane * 16;
      int row = ofs >> 6;
      int cole = (ofs & 63) >> 1;
      gload_lds16(A + (size_t)(m0 + row) * K + k0 + cole, (char*)As + wofs);
      gload_lds16(Bt + (size_t)(n0 + row) * K + k0 + cole, (char*)Bs + wofs);
    }
    __syncthreads();
    bf16x8 af[4], bfr[4];
    for (int mi = 0; mi < 4; ++mi)
      af[mi] = *(const bf16x8*)(As + (wr * 64 + mi * 16 + fr) * 32 + fk);
    for (int ni = 0; ni < 4; ++ni)
      bfr[ni] = *(const bf16x8*)(Bs + (wc * 64 + ni * 16 + fr) * 32 + fk);
    for (int mi = 0; mi < 4; ++mi)
      for (int ni = 0; ni < 4; ++ni)
        acc[mi][ni] =
            __builtin_amdgcn_mfma_f32_16x16x32_bf16(af[mi], bfr[ni], acc[mi][ni], 0, 0, 0);
  }

  if (MODE == 3) {
    float* O = (float*)outp;
    for (int mi = 0; mi < 4; ++mi) {
      int rowb = m0 + wr * 64 + mi * 16 + (lane >> 4) * 4;
      for (int ni = 0; ni < 4; ++ni) {
        int col = n0 + wc * 64 + ni * 16 + fr;
        float bv = bias[col];
        for (int r = 0; r < 4; ++r)
          O[(size_t)(rowb + r) * N + col] = acc[mi][ni][r] + bv;
      }
    }
  } else if (MODE == 2) {
    u16* O = (u16*)outp;
    for (int mi = 0; mi < 4; ++mi) {
      int rowb = m0 + wr * 64 + mi * 16 + (lane >> 4) * 4;
      int bb2 = rowb >> 11, s0 = rowb & (S_ - 1);
      for (int ni = 0; ni < 4; ++ni) {
        int col = n0 + wc * 64 + ni * 16 + fr;
        int hh = col >> 6, dh = col & 63;
        float bv = bias[col];
        us4 pk;
        for (int r = 0; r < 4; ++r) pk[r] = f2bf(acc[mi][ni][r] + bv);
        *(us4*)(O + ((size_t)(bb2 * H_ + hh) * DH_ + dh) * S_ + s0) = pk;
      }
    }
  } else {
    u16* O = (u16*)outp;
    for (int mi = 0; mi < 4; ++mi) {
      int rowb = m0 + wr * 64 + mi * 16 + (lane >> 4) * 4;
      for (int ni = 0; ni < 4; ++ni) {
        int col = n0 + wc * 64 + ni * 16 + fr;
        int hh = col >> 6, dh = col & 63;
        float bv = bias[col];
        for (int r = 0; r < 4; ++r) {
          int row = rowb + r;
          int bb2 = row >> 11, s = row & (S_ - 1);
          float v = acc[mi][ni][r] + bv;
          if (MODE == 0) v *= 0.125f;  // fold 1/sqrt(DH) into Q
          O[((size_t)(bb2 * H_ + hh) * S_ + s) * DH_ + dh] = f2bf(v);
        }
      }
    }
  }
}

// ---------------- flash attention, swapped-QK^T + in-block split-K ----------------
// grid (S/32=64 qblocks, B*H=32), 256 threads = 4 waves = 2 qsub x 2 ksplit.
// Each wave: 16 q-rows (q = q0w + fr, lane-owned), half of the key tiles.
// Qh,Kh [B][H][S][64] bf16 (Q pre-scaled 1/8), Vt [B][H][64][S] bf16.
// rel_bias fp32 [H][S][S]. Causal hard-coded. Output bf16 [M][1024].
__global__ __launch_bounds__(256, 4) void attn_kernel(const u16* __restrict__ Qh,
                                                      const u16* __restrict__ Kh,
                                                      const u16* __restrict__ Vt,
                                                      const float* __restrict__ relb,
                                                      u16* __restrict__ attnout) {
  int qblk = blockIdx.x;
  int bh = blockIdx.y;
  int b = bh >> 4, h = bh & 15;
  int lane = threadIdx.x & 63, wave = threadIdx.x >> 6;
  int qsub = wave & 1, ks = wave >> 1;
  int fr = lane & 15, g = lane >> 4;

  __shared__ float accL[2][16][64];  // ksplit1 partial acc per qsub
  __shared__ float mL[2][2][16];     // [ks][qsub][q16]
  __shared__ float lL[2][2][16];

  int q0w = qblk * 32 + qsub * 16;
  int qme = q0w + fr;                       // this lane's q-row (softmax state)
  const u16* Qb = Qh + ((size_t)bh * S_ + q0w) * DH_;
  bf16x8 qf0 = *(const bf16x8*)(Qb + fr * DH_ + 8 * g);
  bf16x8 qf1 = *(const bf16x8*)(Qb + fr * DH_ + 32 + 8 * g);

  const u16* Kp = Kh + (size_t)bh * S_ * DH_ + fr * DH_ + 8 * g;
  const float* Bp = relb + (size_t)h * S_ * S_ + (size_t)qme * S_ + 4 * g;
  const u16* Vp = Vt + (size_t)bh * DH_ * S_ + fr * S_ + 4 * g;

  f32x4 acc[4];
  const f32x4 vzero = {0.f, 0.f, 0.f, 0.f};
  for (int f = 0; f < 4; ++f) acc[f] = vzero;
  float m = -1.0e4f, l = 0.f;   // m init must be >> -1e30 so masked-only tiles give p=0

  int T = qblk + 1;              // 32-key tiles covering keys <= q0+31
  int half = (T + 1) >> 1;
  int tb = ks ? half : 0, te = ks ? T : half;

  bf16x8 ka0, ka1, kc0, kc1;
  f32x4 bi0, bi1;
  if (tb < te) {
    size_t kb = (size_t)tb * 32;
    ka0 = *(const bf16x8*)(Kp + kb * DH_);
    ka1 = *(const bf16x8*)(Kp + kb * DH_ + 32);
    kc0 = *(const bf16x8*)(Kp + (kb + 16) * DH_);
    kc1 = *(const bf16x8*)(Kp + (kb + 16) * DH_ + 32);
    bi0 = *(const f32x4*)(Bp + kb);
    bi1 = *(const f32x4*)(Bp + kb + 16);
  }

  for (int t = tb; t < te; ++t) {
    int kb = t * 32;
    bool hasn = (t + 1 < te);
    bf16x8 na0, na1, nc0, nc1;
    f32x4 ni0, ni1;
    if (hasn) {
      size_t kn = (size_t)kb + 32;
      na0 = *(const bf16x8*)(Kp + kn * DH_);
      na1 = *(const bf16x8*)(Kp + kn * DH_ + 32);
      nc0 = *(const bf16x8*)(Kp + (kn + 16) * DH_);
      nc1 = *(const bf16x8*)(Kp + (kn + 16) * DH_ + 32);
      ni0 = *(const f32x4*)(Bp + kn);
      ni1 = *(const f32x4*)(Bp + kn + 16);
    }
    // V loads for current tile (k permuted to match in-register P layout)
    union { us4 hf[2]; bf16x8 v; } vv[4];
    for (int f = 0; f < 4; ++f) {
      vv[f].hf[0] = *(const us4*)(Vp + (size_t)f * 16 * S_ + kb);
      vv[f].hf[1] = *(const us4*)(Vp + (size_t)f * 16 * S_ + kb + 16);
    }
    // swapped QK^T: C[k][q], lane holds k = kb+16c+4g+r for q = qme
    f32x4 s0 = vzero, s1 = vzero;
    s0 = __builtin_amdgcn_mfma_f32_16x16x32_bf16(ka0, qf0, s0, 0, 0, 0);
    s0 = __builtin_amdgcn_mfma_f32_16x16x32_bf16(ka1, qf1, s0, 0, 0, 0);
    s1 = __builtin_amdgcn_mfma_f32_16x16x32_bf16(kc0, qf0, s1, 0, 0, 0);
    s1 = __builtin_amdgcn_mfma_f32_16x16x32_bf16(kc1, qf1, s1, 0, 0, 0);
    for (int r = 0; r < 4; ++r) {
      int k0 = kb + 4 * g + r;
      s0[r] = (k0 <= qme) ? s0[r] + bi0[r] : -1e30f;
      s1[r] = (k0 + 16 <= qme) ? s1[r] + bi1[r] : -1e30f;
    }
    // row max: 7 in-lane + 2 shfl (lanes fr,fr+16,fr+32,fr+48 share q)
    float pm = fmaxf(fmaxf(fmaxf(s0[0], s0[1]), fmaxf(s0[2], s0[3])),
                     fmaxf(fmaxf(s1[0], s1[1]), fmaxf(s1[2], s1[3])));
    pm = fmaxf(pm, __shfl_xor(pm, 16));
    pm = fmaxf(pm, __shfl_xor(pm, 32));
    // defer-max: only rescale when max grows > 8 (first real tile always triggers)
    if (!__all(pm - m <= 8.0f)) {
      float mn = fmaxf(m, pm);
      float corr = __expf(m - mn);
      m = mn;
      l *= corr;
      float c0 = __shfl(corr, 4 * g + 0);
      float c1 = __shfl(corr, 4 * g + 1);
      float c2 = __shfl(corr, 4 * g + 2);
      float c3 = __shfl(corr, 4 * g + 3);
      for (int f = 0; f < 4; ++f) {
        acc[f][0] *= c0; acc[f][1] *= c1; acc[f][2] *= c2; acc[f][3] *= c3;
      }
    }
    float p0[4], p1[4], rs = 0.f;
    for (int r = 0; r < 4; ++r) {
      p0[r] = __expf(s0[r] - m);
      p1[r] = __expf(s1[r] - m);
      rs += p0[r] + p1[r];
    }
    rs += __shfl_xor(rs, 16);
    rs += __shfl_xor(rs, 32);
    l += rs;
    union { u16 u[8]; bf16x8 v; } pp;
    for (int r = 0; r < 4; ++r) {
      pp.u[r] = f2bf(p0[r]);
      pp.u[4 + r] = f2bf(p1[r]);
    }
    for (int f = 0; f < 4; ++f)
      acc[f] = __builtin_amdgcn_mfma_f32_16x16x32_bf16(pp.v, vv[f].v, acc[f], 0, 0, 0);
    if (hasn) {
      ka0 = na0; ka1 = na1; kc0 = nc0; kc1 = nc1;
      bi0 = ni0; bi1 = ni1;
    }
  }

  // merge the two k-splits via LDS
  if (ks == 1) {
    for (int f = 0; f < 4; ++f)
      for (int r = 0; r < 4; ++r)
        accL[qsub][4 * g + r][16 * f + fr] = acc[f][r];
  }
  if (lane < 16) {
    mL[ks][qsub][lane] = m;
    lL[ks][qsub][lane] = l;
  }
  __syncthreads();
  if (ks == 0) {
    for (int r = 0; r < 4; ++r) {
      int qq = 4 * g + r;
      float m0 = mL[0][qsub][qq], l0 = lL[0][qsub][qq];
      float m1 = mL[1][qsub][qq], l1 = lL[1][qsub][qq];
      float M = fmaxf(m0, m1);
      float w0 = __expf(m0 - M), w1 = __expf(m1 - M);
      float inv = 1.f / (l0 * w0 + l1 * w1);
      u16* ob = attnout + ((size_t)b * S_ + q0w + qq) * D_ + h * 64;
      for (int f = 0; f < 4; ++f) {
        float v = (acc[f][r] * w0 + accL[qsub][qq][16 * f + fr] * w1) * inv;
        ob[16 * f + fr] = f2bf(v);
      }
    }
  }
}

extern "C" void kernel_launch(void* const* d_in, const int* in_sizes, int n_in,
                              void* d_out, int out_size, void* d_ws, size_t ws_size,
                              hipStream_t stream) {
  const float* q = (const float*)d_in[0];
  const float* k = (const float*)d_in[1];
  const float* v = (const float*)d_in[2];
  const float* rb = (const float*)d_in[4];
  const float* Wq = (const float*)d_in[5];
  const float* bq = (const float*)d_in[6];
  const float* Wk = (const float*)d_in[7];
  const float* bk = (const float*)d_in[8];
  const float* Wv = (const float*)d_in[9];
  const float* bv = (const float*)d_in[10];
  const float* Wo = (const float*)d_in[11];
  const float* bo = (const float*)d_in[12];
  float* out = (float*)d_out;

  char* ws = (char*)d_ws;
  const size_t SZ = (size_t)M_ * D_ * 2;
  u16* Qh = (u16*)(ws);
  u16* Kh = (u16*)(ws + SZ);
  u16* Vt = (u16*)(ws + 2 * SZ);
  u16* Xb = (u16*)(ws + 3 * SZ);
  u16* Wt = (u16*)(ws + 4 * SZ);

  const int n4 = M_ * D_ / 4;
  dim3 tgrid(32, 32), tblk(32, 8);

  transpose_cvt_kernel<<<tgrid, tblk, 0, stream>>>(Wq, Wt + 0 * (size_t)D_ * D_);
  transpose_cvt_kernel<<<tgrid, tblk, 0, stream>>>(Wk, Wt + 1 * (size_t)D_ * D_);
  transpose_cvt_kernel<<<tgrid, tblk, 0, stream>>>(Wv, Wt + 2 * (size_t)D_ * D_);
  transpose_cvt_kernel<<<tgrid, tblk, 0, stream>>>(Wo, Wt + 3 * (size_t)D_ * D_);

  dim3 ggrid(M_ / 128, D_ / 128);

  cvt_kernel<<<n4 / 256, 256, 0, stream>>>(q, Xb, n4);
  gemm_bt<0><<<ggrid, 256, 0, stream>>>(Xb, Wt + 0 * (size_t)D_ * D_, bq, Qh, M_, D_, D_);
  cvt_kernel<<<n4 / 256, 256, 0, stream>>>(k, Xb, n4);
  gemm_bt<1><<<ggrid, 256, 0, stream>>>(Xb, Wt + 1 * (size_t)D_ * D_, bk, Kh, M_, D_, D_);
  cvt_kernel<<<n4 / 256, 256, 0, stream>>>(v, Xb, n4);
  gemm_bt<2><<<ggrid, 256, 0, stream>>>(Xb, Wt + 2 * (size_t)D_ * D_, bv, Vt, M_, D_, D_);

  attn_kernel<<<dim3(S_ / 32, B_ * H_), 256, 0, stream>>>(Qh, Kh, Vt, rb, Xb);

  gemm_bt<3><<<ggrid, 256, 0, stream>>>(Xb, Wt + 3 * (size_t)D_ * D_, bo, out, M_, D_, D_);
}

// Round 3
// 215.301 us; speedup vs baseline: 2.1634x; 2.1634x over previous
//
#include <hip/hip_runtime.h>

typedef unsigned short u16;
typedef __attribute__((ext_vector_type(8))) short bf16x8;
typedef __attribute__((ext_vector_type(4))) float f32x4;
typedef __attribute__((ext_vector_type(4))) unsigned short us4;

#define B_ 2
#define S_ 2048
#define D_ 1024
#define H_ 16
#define DH_ 64
#define M_ 4096 /* B*S */

__device__ __forceinline__ u16 f2bf(float f) {
  unsigned int u = __builtin_bit_cast(unsigned int, f);
  u += 0x7FFFu + ((u >> 16) & 1u);   // RNE
  return (u16)(u >> 16);
}

__device__ __forceinline__ void gload_lds16(const void* g, void* l) {
  __builtin_amdgcn_global_load_lds(
      (__attribute__((address_space(1))) void*)(g),
      (__attribute__((address_space(3))) void*)(l),
      16, 0, 0);
}

// ---------------- fp32 -> bf16 elementwise convert (vectorized) ----------------
__global__ __launch_bounds__(256) void cvt_kernel(const float* __restrict__ in,
                                                  u16* __restrict__ out, int n4) {
  int i = blockIdx.x * 256 + threadIdx.x;
  if (i >= n4) return;
  float4 v = ((const float4*)in)[i];
  us4 o;
  o[0] = f2bf(v.x); o[1] = f2bf(v.y); o[2] = f2bf(v.z); o[3] = f2bf(v.w);
  ((us4*)out)[i] = o;
}

// ---------------- W [K][N] fp32 -> Wt [N][K] bf16 (LDS tile transpose) ----------------
__global__ __launch_bounds__(256) void transpose_cvt_kernel(const float* __restrict__ W,
                                                            u16* __restrict__ Wt) {
  __shared__ float tile[32][33];
  int tx = threadIdx.x, ty = threadIdx.y;
  int x = blockIdx.x * 32 + tx;
  for (int j = 0; j < 32; j += 8)
    tile[ty + j][tx] = W[(size_t)(blockIdx.y * 32 + ty + j) * D_ + x];
  __syncthreads();
  int x2 = blockIdx.y * 32 + tx;
  for (int j = 0; j < 32; j += 8)
    Wt[(size_t)(blockIdx.x * 32 + ty + j) * D_ + x2] = f2bf(tile[tx][ty + j]);
}

// ---------------- GEMM: C[m][n] = sum_k A[m][k]*Bt[n][k] + bias[n] ----------------
template <int MODE>
__global__ __launch_bounds__(256) void gemm_bt(const u16* __restrict__ A,
                                               const u16* __restrict__ Bt,
                                               const float* __restrict__ bias,
                                               void* __restrict__ outp,
                                               int M, int N, int K) {
  __shared__ u16 As[128 * 32];
  __shared__ u16 Bs[128 * 32];
  int tid = threadIdx.x;
  int lane = tid & 63, wave = tid >> 6;
  int m0 = blockIdx.x * 128, n0 = blockIdx.y * 128;
  int wr = wave >> 1, wc = wave & 1;
  int fr = lane & 15, fk = (lane >> 4) * 8;

  f32x4 acc[4][4];
  const f32x4 vzero = {0.f, 0.f, 0.f, 0.f};
  for (int i = 0; i < 4; ++i)
    for (int j = 0; j < 4; ++j) acc[i][j] = vzero;

  for (int k0 = 0; k0 < K; k0 += 32) {
    if (k0) __syncthreads();
    for (int i = 0; i < 2; ++i) {
      int wofs = ((i * 4 + wave) << 10);
      int ofs = wofs + lane * 16;
      int row = ofs >> 6;
      int cole = (ofs & 63) >> 1;
      gload_lds16(A + (size_t)(m0 + row) * K + k0 + cole, (char*)As + wofs);
      gload_lds16(Bt + (size_t)(n0 + row) * K + k0 + cole, (char*)Bs + wofs);
    }
    __syncthreads();
    bf16x8 af[4], bfr[4];
    for (int mi = 0; mi < 4; ++mi)
      af[mi] = *(const bf16x8*)(As + (wr * 64 + mi * 16 + fr) * 32 + fk);
    for (int ni = 0; ni < 4; ++ni)
      bfr[ni] = *(const bf16x8*)(Bs + (wc * 64 + ni * 16 + fr) * 32 + fk);
    for (int mi = 0; mi < 4; ++mi)
      for (int ni = 0; ni < 4; ++ni)
        acc[mi][ni] =
            __builtin_amdgcn_mfma_f32_16x16x32_bf16(af[mi], bfr[ni], acc[mi][ni], 0, 0, 0);
  }

  if (MODE == 3) {
    float* O = (float*)outp;
    for (int mi = 0; mi < 4; ++mi) {
      int rowb = m0 + wr * 64 + mi * 16 + (lane >> 4) * 4;
      for (int ni = 0; ni < 4; ++ni) {
        int col = n0 + wc * 64 + ni * 16 + fr;
        float bv = bias[col];
        for (int r = 0; r < 4; ++r)
          O[(size_t)(rowb + r) * N + col] = acc[mi][ni][r] + bv;
      }
    }
  } else if (MODE == 2) {
    u16* O = (u16*)outp;
    for (int mi = 0; mi < 4; ++mi) {
      int rowb = m0 + wr * 64 + mi * 16 + (lane >> 4) * 4;
      int bb2 = rowb >> 11, s0 = rowb & (S_ - 1);
      for (int ni = 0; ni < 4; ++ni) {
        int col = n0 + wc * 64 + ni * 16 + fr;
        int hh = col >> 6, dh = col & 63;
        float bv = bias[col];
        us4 pk;
        for (int r = 0; r < 4; ++r) pk[r] = f2bf(acc[mi][ni][r] + bv);
        *(us4*)(O + ((size_t)(bb2 * H_ + hh) * DH_ + dh) * S_ + s0) = pk;
      }
    }
  } else {
    u16* O = (u16*)outp;
    for (int mi = 0; mi < 4; ++mi) {
      int rowb = m0 + wr * 64 + mi * 16 + (lane >> 4) * 4;
      for (int ni = 0; ni < 4; ++ni) {
        int col = n0 + wc * 64 + ni * 16 + fr;
        int hh = col >> 6, dh = col & 63;
        float bv = bias[col];
        for (int r = 0; r < 4; ++r) {
          int row = rowb + r;
          int bb2 = row >> 11, s = row & (S_ - 1);
          float v = acc[mi][ni][r] + bv;
          if (MODE == 0) v *= 0.125f;  // fold 1/sqrt(DH) into Q
          O[((size_t)(bb2 * H_ + hh) * S_ + s) * DH_ + dh] = f2bf(v);
        }
      }
    }
  }
}

// ---------------- flash attention v3: LDS-staged K/V, batch-paired bias ----------------
// grid: 512 flat blocks -> (h, stripe) with XCD-aware swizzle (each XCD owns 2 heads;
// heavy stripes dispatched first). 512 threads = 8 waves = 2 batches x 4 q-subtiles
// of 16 rows. Stripe = 64 q-rows. K/V tiles (64 keys) staged in LDS, double-buffered,
// via global_load_lds with pre-swizzled source (XOR ((row&7)<<4)) + swizzled ds_read.
// Qh,Kh [B][H][S][64] bf16 (Q pre-scaled 1/8), Vt [B][H][64][S] bf16.
// rel_bias fp32 [H][S][S] read once per block (both batches share). Causal hard-coded.
__global__ __launch_bounds__(512) void attn_kernel(const u16* __restrict__ Qh,
                                                   const u16* __restrict__ Kh,
                                                   const u16* __restrict__ Vt,
                                                   const float* __restrict__ relb,
                                                   u16* __restrict__ attnout) {
  __shared__ u16 KVs[2][2][2][4096];  // [K=0/V=1][batch][buf][64*64 bf16] = 64 KB

  int fid = blockIdx.x;
  int xcd = fid & 7, rr = fid >> 3;
  int h = xcd * 2 + (rr & 1);
  int s = 31 - (rr >> 1);            // heavy stripes first

  int w = threadIdx.x >> 6, lane = threadIdx.x & 63;
  int fr = lane & 15, g = lane >> 4;
  int b = w >> 2, qw = w & 3;
  int q0w = s * 64 + qw * 16;
  int qme = q0w + fr;
  int bh = b * H_ + h;
  int sx = (fr & 7) << 4;            // read-side XOR swizzle

  // staging duty: waves (w, w+4) pair on tensor w&3; kind 0=K,1=V; batch sb=w&1
  int kind = (w & 3) >> 1, sb = w & 1;
  int i0 = (w >> 2) * 4;
  int srow_lo = lane >> 3;           // row contribution from lane
  int scb = ((lane & 7) * 16);       // linear col byte in LDS

  const u16* Qb = Qh + ((size_t)bh * S_ + q0w) * DH_;
  bf16x8 qf0 = *(const bf16x8*)(Qb + fr * DH_ + 8 * g);
  bf16x8 qf1 = *(const bf16x8*)(Qb + fr * DH_ + 32 + 8 * g);

  const float* Bq = relb + (size_t)h * S_ * S_ + (size_t)qme * S_ + 4 * g;

  f32x4 acc[4];
  const f32x4 vzero = {0.f, 0.f, 0.f, 0.f};
  for (int f4 = 0; f4 < 4; ++f4) acc[f4] = vzero;
  float m = -1.0e4f, l = 0.f;

  int T = s + 1;                     // 64-key tiles

  auto STAGE = [&](int buf, int kb) {
    for (int i = 0; i < 4; ++i) {
      int ii = i0 + i;
      int row = ii * 8 + srow_lo;
      int cbs = scb ^ ((row & 7) << 4);   // inverse-swizzled source col (XOR is involution)
      const u16* src;
      if (kind == 0)
        src = Kh + ((size_t)(sb * H_ + h) * S_ + kb + row) * DH_ + (cbs >> 1);
      else
        src = Vt + ((size_t)(sb * H_ + h) * DH_ + row) * S_ + kb + (cbs >> 1);
      gload_lds16(src, &KVs[kind][sb][buf][ii * 512]);
    }
  };

  f32x4 bi[4], bn[4];
  STAGE(0, 0);
  for (int c = 0; c < 4; ++c) bi[c] = *(const f32x4*)(Bq + 16 * c);
  __syncthreads();

  for (int t = 0; t < T; ++t) {
    int kb = t * 64;
    int buf = t & 1;
    if (t + 1 < T) {
      STAGE(buf ^ 1, kb + 64);
      for (int c = 0; c < 4; ++c) bn[c] = *(const f32x4*)(Bq + kb + 64 + 16 * c);
    }
    const char* Kt = (const char*)&KVs[0][b][buf][0];
    const char* Vl = (const char*)&KVs[1][b][buf][0];

    // swapped QK^T: lane(fr,g) gets scores for q=qme, keys kb+16c+4g+r
    f32x4 sc[4];
    for (int c = 0; c < 4; ++c) {
      bf16x8 k0 = *(const bf16x8*)(Kt + (16 * c + fr) * 128 + ((16 * g) ^ sx));
      bf16x8 k1 = *(const bf16x8*)(Kt + (16 * c + fr) * 128 + ((64 + 16 * g) ^ sx));
      f32x4 z = vzero;
      z = __builtin_amdgcn_mfma_f32_16x16x32_bf16(k0, qf0, z, 0, 0, 0);
      z = __builtin_amdgcn_mfma_f32_16x16x32_bf16(k1, qf1, z, 0, 0, 0);
      sc[c] = z;
    }
    for (int c = 0; c < 4; ++c)
      for (int r = 0; r < 4; ++r) {
        int key = kb + 16 * c + 4 * g + r;
        sc[c][r] = (key <= qme) ? sc[c][r] + bi[c][r] : -1e30f;
      }
    // row max over 16 in-lane + 2 shfl (lanes fr,fr+16,fr+32,fr+48 share q)
    float pm = fmaxf(fmaxf(fmaxf(fmaxf(sc[0][0], sc[0][1]), fmaxf(sc[0][2], sc[0][3])),
                           fmaxf(fmaxf(sc[1][0], sc[1][1]), fmaxf(sc[1][2], sc[1][3]))),
                     fmaxf(fmaxf(fmaxf(sc[2][0], sc[2][1]), fmaxf(sc[2][2], sc[2][3])),
                           fmaxf(fmaxf(sc[3][0], sc[3][1]), fmaxf(sc[3][2], sc[3][3]))));
    pm = fmaxf(pm, __shfl_xor(pm, 16));
    pm = fmaxf(pm, __shfl_xor(pm, 32));
    // defer-max (T13, THR=8)
    if (!__all(pm - m <= 8.0f)) {
      float mn = fmaxf(m, pm);
      float corr = __expf(m - mn);
      m = mn;
      l *= corr;
      float c0 = __shfl(corr, 4 * g + 0);
      float c1 = __shfl(corr, 4 * g + 1);
      float c2 = __shfl(corr, 4 * g + 2);
      float c3 = __shfl(corr, 4 * g + 3);
      for (int f4 = 0; f4 < 4; ++f4) {
        acc[f4][0] *= c0; acc[f4][1] *= c1; acc[f4][2] *= c2; acc[f4][3] *= c3;
      }
    }
    float p[4][4], rs = 0.f;
    for (int c = 0; c < 4; ++c)
      for (int r = 0; r < 4; ++r) {
        p[c][r] = __expf(sc[c][r] - m);
        rs += p[c][r];
      }
    rs += __shfl_xor(rs, 16);
    rs += __shfl_xor(rs, 32);
    l += rs;
    union { u16 u[8]; bf16x8 v; } pp[2];
    for (int cc = 0; cc < 2; ++cc)
      for (int r = 0; r < 4; ++r) {
        pp[cc].u[r] = f2bf(p[2 * cc][r]);
        pp[cc].u[4 + r] = f2bf(p[2 * cc + 1][r]);
      }
    // PV: acc[f4] += P(16q x 32k) @ V(32k x 16dh), V keys permuted to match P layout
    for (int f4 = 0; f4 < 4; ++f4) {
      for (int cc = 0; cc < 2; ++cc) {
        union { us4 hh[2]; bf16x8 v; } vf;
        vf.hh[0] = *(const us4*)(Vl + (f4 * 16 + fr) * 128 + ((cc * 64 + 8 * g) ^ sx));
        vf.hh[1] = *(const us4*)(Vl + (f4 * 16 + fr) * 128 + ((cc * 64 + 32 + 8 * g) ^ sx));
        acc[f4] = __builtin_amdgcn_mfma_f32_16x16x32_bf16(pp[cc].v, vf.v, acc[f4], 0, 0, 0);
      }
    }
    for (int c = 0; c < 4; ++c) bi[c] = bn[c];
    __syncthreads();
  }

  // epilogue: acc row q = q0w+4g+r, col dh = f4*16+fr; l owned by lane (q index) fr
  float il = 1.f / l;
  for (int r = 0; r < 4; ++r) {
    float ilr = __shfl(il, 4 * g + r);
    int qq = q0w + 4 * g + r;
    u16* ob = attnout + ((size_t)b * S_ + qq) * D_ + h * 64;
    for (int f4 = 0; f4 < 4; ++f4) ob[f4 * 16 + fr] = f2bf(acc[f4][r] * ilr);
  }
}

extern "C" void kernel_launch(void* const* d_in, const int* in_sizes, int n_in,
                              void* d_out, int out_size, void* d_ws, size_t ws_size,
                              hipStream_t stream) {
  const float* q = (const float*)d_in[0];
  const float* k = (const float*)d_in[1];
  const float* v = (const float*)d_in[2];
  const float* rb = (const float*)d_in[4];
  const float* Wq = (const float*)d_in[5];
  const float* bq = (const float*)d_in[6];
  const float* Wk = (const float*)d_in[7];
  const float* bk = (const float*)d_in[8];
  const float* Wv = (const float*)d_in[9];
  const float* bv = (const float*)d_in[10];
  const float* Wo = (const float*)d_in[11];
  const float* bo = (const float*)d_in[12];
  float* out = (float*)d_out;

  char* ws = (char*)d_ws;
  const size_t SZ = (size_t)M_ * D_ * 2;
  u16* Qh = (u16*)(ws);
  u16* Kh = (u16*)(ws + SZ);
  u16* Vt = (u16*)(ws + 2 * SZ);
  u16* Xb = (u16*)(ws + 3 * SZ);
  u16* Wt = (u16*)(ws + 4 * SZ);

  const int n4 = M_ * D_ / 4;
  dim3 tgrid(32, 32), tblk(32, 8);

  transpose_cvt_kernel<<<tgrid, tblk, 0, stream>>>(Wq, Wt + 0 * (size_t)D_ * D_);
  transpose_cvt_kernel<<<tgrid, tblk, 0, stream>>>(Wk, Wt + 1 * (size_t)D_ * D_);
  transpose_cvt_kernel<<<tgrid, tblk, 0, stream>>>(Wv, Wt + 2 * (size_t)D_ * D_);
  transpose_cvt_kernel<<<tgrid, tblk, 0, stream>>>(Wo, Wt + 3 * (size_t)D_ * D_);

  dim3 ggrid(M_ / 128, D_ / 128);

  cvt_kernel<<<n4 / 256, 256, 0, stream>>>(q, Xb, n4);
  gemm_bt<0><<<ggrid, 256, 0, stream>>>(Xb, Wt + 0 * (size_t)D_ * D_, bq, Qh, M_, D_, D_);
  cvt_kernel<<<n4 / 256, 256, 0, stream>>>(k, Xb, n4);
  gemm_bt<1><<<ggrid, 256, 0, stream>>>(Xb, Wt + 1 * (size_t)D_ * D_, bk, Kh, M_, D_, D_);
  cvt_kernel<<<n4 / 256, 256, 0, stream>>>(v, Xb, n4);
  gemm_bt<2><<<ggrid, 256, 0, stream>>>(Xb, Wt + 2 * (size_t)D_ * D_, bv, Vt, M_, D_, D_);

  attn_kernel<<<dim3(512), 512, 0, stream>>>(Qh, Kh, Vt, rb, Xb);

  gemm_bt<3><<<ggrid, 256, 0, stream>>>(Xb, Wt + 3 * (size_t)D_ * D_, bo, out, M_, D_, D_);
}

// Round 4
// 197.436 us; speedup vs baseline: 2.3592x; 1.0905x over previous
//
#include <hip/hip_runtime.h>

typedef unsigned short u16;
typedef __attribute__((ext_vector_type(8))) short bf16x8;
typedef __attribute__((ext_vector_type(4))) float f32x4;
typedef __attribute__((ext_vector_type(4))) unsigned short us4;

#define B_ 2
#define S_ 2048
#define D_ 1024
#define H_ 16
#define DH_ 64
#define M_ 4096 /* B*S */

__device__ __forceinline__ u16 f2bf(float f) {
  unsigned int u = __builtin_bit_cast(unsigned int, f);
  u += 0x7FFFu + ((u >> 16) & 1u);   // RNE
  return (u16)(u >> 16);
}

__device__ __forceinline__ void gload_lds16(const void* g, void* l) {
  __builtin_amdgcn_global_load_lds(
      (__attribute__((address_space(1))) void*)(g),
      (__attribute__((address_space(3))) void*)(l),
      16, 0, 0);
}

// ---------------- weight prep: W[z] [K][N] fp32 -> Wt[z] [N][K] bf16 ----------------
__global__ __launch_bounds__(256) void wprep_kernel(const float* __restrict__ W0,
                                                    const float* __restrict__ W1,
                                                    const float* __restrict__ W2,
                                                    const float* __restrict__ W3,
                                                    u16* __restrict__ Wt) {
  __shared__ float tile[32][33];
  int z = blockIdx.z;
  const float* W = (z == 0) ? W0 : (z == 1) ? W1 : (z == 2) ? W2 : W3;
  u16* out = Wt + (size_t)z * D_ * D_;
  int tx = threadIdx.x, ty = threadIdx.y;
  int x = blockIdx.x * 32 + tx;
  for (int j = 0; j < 32; j += 8)
    tile[ty + j][tx] = W[(size_t)(blockIdx.y * 32 + ty + j) * D_ + x];
  __syncthreads();
  int x2 = blockIdx.y * 32 + tx;
  for (int j = 0; j < 32; j += 8)
    out[(size_t)(blockIdx.x * 32 + ty + j) * D_ + x2] = f2bf(tile[tx][ty + j]);
}

// ---------------- fused QKV GEMM: C = fp32A @ Wt^T + bias, 3 outputs via grid.z ------
// A fp32 [M][1024] converted to bf16 during LDS staging (reg-stage A, gload_lds B).
// z=0: Qh [B][H][S][DH] bf16 scaled 1/8; z=1: Kh same layout; z=2: Vt [B][H][DH][S].
__global__ __launch_bounds__(256) void gemm_qkv(const float* __restrict__ qin,
                                                const float* __restrict__ kin,
                                                const float* __restrict__ vin,
                                                const u16* __restrict__ Wt,
                                                const float* __restrict__ bq,
                                                const float* __restrict__ bk,
                                                const float* __restrict__ bv,
                                                u16* __restrict__ Qh,
                                                u16* __restrict__ Kh,
                                                u16* __restrict__ Vt) {
  __shared__ u16 As[128 * 32];
  __shared__ u16 Bs[128 * 32];
  int z = blockIdx.z;
  const float* A = (z == 0) ? qin : (z == 1) ? kin : vin;
  const u16* Bt = Wt + (size_t)z * D_ * D_;
  const float* bias = (z == 0) ? bq : (z == 1) ? bk : bv;
  u16* O = (z == 0) ? Qh : (z == 1) ? Kh : Vt;

  int tid = threadIdx.x;
  int lane = tid & 63, wave = tid >> 6;
  int m0 = blockIdx.x * 128, n0 = blockIdx.y * 128;
  int wr = wave >> 1, wc = wave & 1;
  int fr = lane & 15, fk = (lane >> 4) * 8;
  int ar = tid >> 3, ac = (tid & 7) * 4;   // A-staging: row, fp32 col

  f32x4 acc[4][4];
  const f32x4 vzero = {0.f, 0.f, 0.f, 0.f};
  for (int i = 0; i < 4; ++i)
    for (int j = 0; j < 4; ++j) acc[i][j] = vzero;

  for (int k0 = 0; k0 < D_; k0 += 32) {
    if (k0) __syncthreads();
    // B tile via async gload_lds (8 KB, 2 passes)
    for (int i = 0; i < 2; ++i) {
      int wofs = ((i * 4 + wave) << 10);
      int ofs = wofs + lane * 16;
      int row = ofs >> 6;
      int cole = (ofs & 63) >> 1;
      gload_lds16(Bt + (size_t)(n0 + row) * D_ + k0 + cole, (char*)Bs + wofs);
    }
    // A tile: fp32 -> bf16 reg-staged (4 x float4 per thread)
    for (int i = 0; i < 4; ++i) {
      int r = ar + i * 32;
      float4 av = *(const float4*)(A + (size_t)(m0 + r) * D_ + k0 + ac);
      us4 o;
      o[0] = f2bf(av.x); o[1] = f2bf(av.y); o[2] = f2bf(av.z); o[3] = f2bf(av.w);
      *(us4*)(As + r * 32 + ac) = o;
    }
    __syncthreads();
    bf16x8 af[4], bfr[4];
    for (int mi = 0; mi < 4; ++mi)
      af[mi] = *(const bf16x8*)(As + (wr * 64 + mi * 16 + fr) * 32 + fk);
    for (int ni = 0; ni < 4; ++ni)
      bfr[ni] = *(const bf16x8*)(Bs + (wc * 64 + ni * 16 + fr) * 32 + fk);
    for (int mi = 0; mi < 4; ++mi)
      for (int ni = 0; ni < 4; ++ni)
        acc[mi][ni] =
            __builtin_amdgcn_mfma_f32_16x16x32_bf16(af[mi], bfr[ni], acc[mi][ni], 0, 0, 0);
  }

  if (z == 2) {  // Vt [B][H][DH][S]
    for (int mi = 0; mi < 4; ++mi) {
      int rowb = m0 + wr * 64 + mi * 16 + (lane >> 4) * 4;
      int bb2 = rowb >> 11, s0 = rowb & (S_ - 1);
      for (int ni = 0; ni < 4; ++ni) {
        int col = n0 + wc * 64 + ni * 16 + fr;
        int hh = col >> 6, dh = col & 63;
        float bv = bias[col];
        us4 pk;
        for (int r = 0; r < 4; ++r) pk[r] = f2bf(acc[mi][ni][r] + bv);
        *(us4*)(O + ((size_t)(bb2 * H_ + hh) * DH_ + dh) * S_ + s0) = pk;
      }
    }
  } else {       // Qh/Kh [B][H][S][DH]
    float scale = (z == 0) ? 0.125f : 1.0f;
    for (int mi = 0; mi < 4; ++mi) {
      int rowb = m0 + wr * 64 + mi * 16 + (lane >> 4) * 4;
      for (int ni = 0; ni < 4; ++ni) {
        int col = n0 + wc * 64 + ni * 16 + fr;
        int hh = col >> 6, dh = col & 63;
        float bv = bias[col];
        for (int r = 0; r < 4; ++r) {
          int row = rowb + r;
          int bb2 = row >> 11, s = row & (S_ - 1);
          O[((size_t)(bb2 * H_ + hh) * S_ + s) * DH_ + dh] = f2bf((acc[mi][ni][r] + bv) * scale);
        }
      }
    }
  }
}

// ---------------- output GEMM: out fp32 = bf16 A @ Wo^T + bo ----------------
__global__ __launch_bounds__(256) void gemm_out(const u16* __restrict__ A,
                                                const u16* __restrict__ Bt,
                                                const float* __restrict__ bias,
                                                float* __restrict__ O) {
  __shared__ u16 As[128 * 32];
  __shared__ u16 Bs[128 * 32];
  int tid = threadIdx.x;
  int lane = tid & 63, wave = tid >> 6;
  int m0 = blockIdx.x * 128, n0 = blockIdx.y * 128;
  int wr = wave >> 1, wc = wave & 1;
  int fr = lane & 15, fk = (lane >> 4) * 8;

  f32x4 acc[4][4];
  const f32x4 vzero = {0.f, 0.f, 0.f, 0.f};
  for (int i = 0; i < 4; ++i)
    for (int j = 0; j < 4; ++j) acc[i][j] = vzero;

  for (int k0 = 0; k0 < D_; k0 += 32) {
    if (k0) __syncthreads();
    for (int i = 0; i < 2; ++i) {
      int wofs = ((i * 4 + wave) << 10);
      int ofs = wofs + lane * 16;
      int row = ofs >> 6;
      int cole = (ofs & 63) >> 1;
      gload_lds16(A + (size_t)(m0 + row) * D_ + k0 + cole, (char*)As + wofs);
      gload_lds16(Bt + (size_t)(n0 + row) * D_ + k0 + cole, (char*)Bs + wofs);
    }
    __syncthreads();
    bf16x8 af[4], bfr[4];
    for (int mi = 0; mi < 4; ++mi)
      af[mi] = *(const bf16x8*)(As + (wr * 64 + mi * 16 + fr) * 32 + fk);
    for (int ni = 0; ni < 4; ++ni)
      bfr[ni] = *(const bf16x8*)(Bs + (wc * 64 + ni * 16 + fr) * 32 + fk);
    for (int mi = 0; mi < 4; ++mi)
      for (int ni = 0; ni < 4; ++ni)
        acc[mi][ni] =
            __builtin_amdgcn_mfma_f32_16x16x32_bf16(af[mi], bfr[ni], acc[mi][ni], 0, 0, 0);
  }

  for (int mi = 0; mi < 4; ++mi) {
    int rowb = m0 + wr * 64 + mi * 16 + (lane >> 4) * 4;
    for (int ni = 0; ni < 4; ++ni) {
      int col = n0 + wc * 64 + ni * 16 + fr;
      float bv = bias[col];
      for (int r = 0; r < 4; ++r)
        O[(size_t)(rowb + r) * D_ + col] = acc[mi][ni][r] + bv;
    }
  }
}

// ---------------- flash attention v3: LDS-staged K/V, batch-paired bias ----------------
__global__ __launch_bounds__(512) void attn_kernel(const u16* __restrict__ Qh,
                                                   const u16* __restrict__ Kh,
                                                   const u16* __restrict__ Vt,
                                                   const float* __restrict__ relb,
                                                   u16* __restrict__ attnout) {
  __shared__ u16 KVs[2][2][2][4096];  // [K=0/V=1][batch][buf][64*64 bf16] = 64 KB

  int fid = blockIdx.x;
  int xcd = fid & 7, rr = fid >> 3;
  int h = xcd * 2 + (rr & 1);
  int s = 31 - (rr >> 1);            // heavy stripes first

  int w = threadIdx.x >> 6, lane = threadIdx.x & 63;
  int fr = lane & 15, g = lane >> 4;
  int b = w >> 2, qw = w & 3;
  int q0w = s * 64 + qw * 16;
  int qme = q0w + fr;
  int bh = b * H_ + h;
  int sx = (fr & 7) << 4;            // read-side XOR swizzle

  int kind = (w & 3) >> 1, sb = w & 1;
  int i0 = (w >> 2) * 4;
  int srow_lo = lane >> 3;
  int scb = ((lane & 7) * 16);

  const u16* Qb = Qh + ((size_t)bh * S_ + q0w) * DH_;
  bf16x8 qf0 = *(const bf16x8*)(Qb + fr * DH_ + 8 * g);
  bf16x8 qf1 = *(const bf16x8*)(Qb + fr * DH_ + 32 + 8 * g);

  const float* Bq = relb + (size_t)h * S_ * S_ + (size_t)qme * S_ + 4 * g;

  f32x4 acc[4];
  const f32x4 vzero = {0.f, 0.f, 0.f, 0.f};
  for (int f4 = 0; f4 < 4; ++f4) acc[f4] = vzero;
  float m = -1.0e4f, l = 0.f;

  int T = s + 1;

  auto STAGE = [&](int buf, int kb) {
    for (int i = 0; i < 4; ++i) {
      int ii = i0 + i;
      int row = ii * 8 + srow_lo;
      int cbs = scb ^ ((row & 7) << 4);
      const u16* src;
      if (kind == 0)
        src = Kh + ((size_t)(sb * H_ + h) * S_ + kb + row) * DH_ + (cbs >> 1);
      else
        src = Vt + ((size_t)(sb * H_ + h) * DH_ + row) * S_ + kb + (cbs >> 1);
      gload_lds16(src, &KVs[kind][sb][buf][ii * 512]);
    }
  };

  f32x4 bi[4], bn[4];
  STAGE(0, 0);
  for (int c = 0; c < 4; ++c) bi[c] = *(const f32x4*)(Bq + 16 * c);
  __syncthreads();

  for (int t = 0; t < T; ++t) {
    int kb = t * 64;
    int buf = t & 1;
    if (t + 1 < T) {
      STAGE(buf ^ 1, kb + 64);
      for (int c = 0; c < 4; ++c) bn[c] = *(const f32x4*)(Bq + kb + 64 + 16 * c);
    }
    const char* Kt = (const char*)&KVs[0][b][buf][0];
    const char* Vl = (const char*)&KVs[1][b][buf][0];

    // swapped QK^T: lane(fr,g) gets scores for q=qme, keys kb+16c+4g+r
    f32x4 sc[4];
    __builtin_amdgcn_s_setprio(1);
    for (int c = 0; c < 4; ++c) {
      bf16x8 k0 = *(const bf16x8*)(Kt + (16 * c + fr) * 128 + ((16 * g) ^ sx));
      bf16x8 k1 = *(const bf16x8*)(Kt + (16 * c + fr) * 128 + ((64 + 16 * g) ^ sx));
      f32x4 z = vzero;
      z = __builtin_amdgcn_mfma_f32_16x16x32_bf16(k0, qf0, z, 0, 0, 0);
      z = __builtin_amdgcn_mfma_f32_16x16x32_bf16(k1, qf1, z, 0, 0, 0);
      sc[c] = z;
    }
    __builtin_amdgcn_s_setprio(0);
    for (int c = 0; c < 4; ++c)
      for (int r = 0; r < 4; ++r) {
        int key = kb + 16 * c + 4 * g + r;
        sc[c][r] = (key <= qme) ? sc[c][r] + bi[c][r] : -1e30f;
      }
    // row max: max3-friendly chain + 2 shfl
    float pm = fmaxf(sc[0][0], sc[0][1]);
    pm = fmaxf(fmaxf(pm, sc[0][2]), sc[0][3]);
    pm = fmaxf(fmaxf(pm, sc[1][0]), sc[1][1]);
    pm = fmaxf(fmaxf(pm, sc[1][2]), sc[1][3]);
    pm = fmaxf(fmaxf(pm, sc[2][0]), sc[2][1]);
    pm = fmaxf(fmaxf(pm, sc[2][2]), sc[2][3]);
    pm = fmaxf(fmaxf(pm, sc[3][0]), sc[3][1]);
    pm = fmaxf(fmaxf(pm, sc[3][2]), sc[3][3]);
    pm = fmaxf(pm, __shfl_xor(pm, 16));
    pm = fmaxf(pm, __shfl_xor(pm, 32));
    // defer-max (T13, THR=8)
    if (!__all(pm - m <= 8.0f)) {
      float mn = fmaxf(m, pm);
      float corr = __expf(m - mn);
      m = mn;
      l *= corr;
      float c0 = __shfl(corr, 4 * g + 0);
      float c1 = __shfl(corr, 4 * g + 1);
      float c2 = __shfl(corr, 4 * g + 2);
      float c3 = __shfl(corr, 4 * g + 3);
      for (int f4 = 0; f4 < 4; ++f4) {
        acc[f4][0] *= c0; acc[f4][1] *= c1; acc[f4][2] *= c2; acc[f4][3] *= c3;
      }
    }
    float p[4][4], rs = 0.f;
    for (int c = 0; c < 4; ++c)
      for (int r = 0; r < 4; ++r) {
        p[c][r] = __expf(sc[c][r] - m);
        rs += p[c][r];
      }
    rs += __shfl_xor(rs, 16);
    rs += __shfl_xor(rs, 32);
    l += rs;
    union { u16 u[8]; bf16x8 v; } pp[2];
    for (int cc = 0; cc < 2; ++cc)
      for (int r = 0; r < 4; ++r) {
        pp[cc].u[r] = f2bf(p[2 * cc][r]);
        pp[cc].u[4 + r] = f2bf(p[2 * cc + 1][r]);
      }
    // PV: acc[f4] += P(16q x 32k) @ V(32k x 16dh)
    __builtin_amdgcn_s_setprio(1);
    for (int f4 = 0; f4 < 4; ++f4) {
      for (int cc = 0; cc < 2; ++cc) {
        union { us4 hh[2]; bf16x8 v; } vf;
        vf.hh[0] = *(const us4*)(Vl + (f4 * 16 + fr) * 128 + ((cc * 64 + 8 * g) ^ sx));
        vf.hh[1] = *(const us4*)(Vl + (f4 * 16 + fr) * 128 + ((cc * 64 + 32 + 8 * g) ^ sx));
        acc[f4] = __builtin_amdgcn_mfma_f32_16x16x32_bf16(pp[cc].v, vf.v, acc[f4], 0, 0, 0);
      }
    }
    __builtin_amdgcn_s_setprio(0);
    for (int c = 0; c < 4; ++c) bi[c] = bn[c];
    __syncthreads();
  }

  float il = 1.f / l;
  for (int r = 0; r < 4; ++r) {
    float ilr = __shfl(il, 4 * g + r);
    int qq = q0w + 4 * g + r;
    u16* ob = attnout + ((size_t)b * S_ + qq) * D_ + h * 64;
    for (int f4 = 0; f4 < 4; ++f4) ob[f4 * 16 + fr] = f2bf(acc[f4][r] * ilr);
  }
}

extern "C" void kernel_launch(void* const* d_in, const int* in_sizes, int n_in,
                              void* d_out, int out_size, void* d_ws, size_t ws_size,
                              hipStream_t stream) {
  const float* q = (const float*)d_in[0];
  const float* k = (const float*)d_in[1];
  const float* v = (const float*)d_in[2];
  const float* rb = (const float*)d_in[4];
  const float* Wq = (const float*)d_in[5];
  const float* bq = (const float*)d_in[6];
  const float* Wk = (const float*)d_in[7];
  const float* bk = (const float*)d_in[8];
  const float* Wv = (const float*)d_in[9];
  const float* bv = (const float*)d_in[10];
  const float* Wo = (const float*)d_in[11];
  const float* bo = (const float*)d_in[12];
  float* out = (float*)d_out;

  char* ws = (char*)d_ws;
  const size_t SZ = (size_t)M_ * D_ * 2;
  u16* Qh = (u16*)(ws);
  u16* Kh = (u16*)(ws + SZ);
  u16* Vt = (u16*)(ws + 2 * SZ);
  u16* Xb = (u16*)(ws + 3 * SZ);          // attn output (bf16 [M][D])
  u16* Wt = (u16*)(ws + 4 * SZ);          // 4 transposed bf16 weights

  // 1. weight prep (one launch, z = which weight)
  wprep_kernel<<<dim3(32, 32, 4), dim3(32, 8), 0, stream>>>(Wq, Wk, Wv, Wo, Wt);

  // 2. fused QKV projection (one launch, z = q/k/v; fp32 A converted in-kernel)
  gemm_qkv<<<dim3(M_ / 128, D_ / 128, 3), 256, 0, stream>>>(q, k, v, Wt, bq, bk, bv,
                                                            Qh, Kh, Vt);

  // 3. attention
  attn_kernel<<<dim3(512), 512, 0, stream>>>(Qh, Kh, Vt, rb, Xb);

  // 4. output projection
  gemm_out<<<dim3(M_ / 128, D_ / 128), 256, 0, stream>>>(Xb, Wt + 3 * (size_t)D_ * D_,
                                                         bo, out);
}

// Round 5
// 190.834 us; speedup vs baseline: 2.4408x; 1.0346x over previous
//
#include <hip/hip_runtime.h>

typedef unsigned short u16;
typedef __attribute__((ext_vector_type(8))) short bf16x8;
typedef __attribute__((ext_vector_type(4))) float f32x4;
typedef __attribute__((ext_vector_type(4))) unsigned short us4;

#define B_ 2
#define S_ 2048
#define D_ 1024
#define H_ 16
#define DH_ 64
#define M_ 4096 /* B*S */

__device__ __forceinline__ u16 f2bf(float f) {
  unsigned int u = __builtin_bit_cast(unsigned int, f);
  u += 0x7FFFu + ((u >> 16) & 1u);   // RNE
  return (u16)(u >> 16);
}

__device__ __forceinline__ void gload_lds16(const void* g, void* l) {
  __builtin_amdgcn_global_load_lds(
      (__attribute__((address_space(1))) void*)(g),
      (__attribute__((address_space(3))) void*)(l),
      16, 0, 0);
}

// ---------------- weight prep: W[z] [K][N] fp32 -> Wt[z] [N][K] bf16 ----------------
__global__ __launch_bounds__(256) void wprep_kernel(const float* __restrict__ W0,
                                                    const float* __restrict__ W1,
                                                    const float* __restrict__ W2,
                                                    const float* __restrict__ W3,
                                                    u16* __restrict__ Wt) {
  __shared__ float tile[32][33];
  int z = blockIdx.z;
  const float* W = (z == 0) ? W0 : (z == 1) ? W1 : (z == 2) ? W2 : W3;
  u16* out = Wt + (size_t)z * D_ * D_;
  int tx = threadIdx.x, ty = threadIdx.y;
  int x = blockIdx.x * 32 + tx;
  for (int j = 0; j < 32; j += 8)
    tile[ty + j][tx] = W[(size_t)(blockIdx.y * 32 + ty + j) * D_ + x];
  __syncthreads();
  int x2 = blockIdx.y * 32 + tx;
  for (int j = 0; j < 32; j += 8)
    out[(size_t)(blockIdx.x * 32 + ty + j) * D_ + x2] = f2bf(tile[tx][ty + j]);
}

// ---------------- fused QKV GEMM (A fp32 converted during staging) ----------------
__global__ __launch_bounds__(256) void gemm_qkv(const float* __restrict__ qin,
                                                const float* __restrict__ kin,
                                                const float* __restrict__ vin,
                                                const u16* __restrict__ Wt,
                                                const float* __restrict__ bq,
                                                const float* __restrict__ bk,
                                                const float* __restrict__ bv,
                                                u16* __restrict__ Qh,
                                                u16* __restrict__ Kh,
                                                u16* __restrict__ Vt) {
  __shared__ u16 As[128 * 32];
  __shared__ u16 Bs[128 * 32];
  int z = blockIdx.z;
  const float* A = (z == 0) ? qin : (z == 1) ? kin : vin;
  const u16* Bt = Wt + (size_t)z * D_ * D_;
  const float* bias = (z == 0) ? bq : (z == 1) ? bk : bv;
  u16* O = (z == 0) ? Qh : (z == 1) ? Kh : Vt;

  int tid = threadIdx.x;
  int lane = tid & 63, wave = tid >> 6;
  int m0 = blockIdx.x * 128, n0 = blockIdx.y * 128;
  int wr = wave >> 1, wc = wave & 1;
  int fr = lane & 15, fk = (lane >> 4) * 8;
  int ar = tid >> 3, ac = (tid & 7) * 4;

  f32x4 acc[4][4];
  const f32x4 vzero = {0.f, 0.f, 0.f, 0.f};
  for (int i = 0; i < 4; ++i)
    for (int j = 0; j < 4; ++j) acc[i][j] = vzero;

  for (int k0 = 0; k0 < D_; k0 += 32) {
    if (k0) __syncthreads();
    for (int i = 0; i < 2; ++i) {
      int wofs = ((i * 4 + wave) << 10);
      int ofs = wofs + lane * 16;
      int row = ofs >> 6;
      int cole = (ofs & 63) >> 1;
      gload_lds16(Bt + (size_t)(n0 + row) * D_ + k0 + cole, (char*)Bs + wofs);
    }
    for (int i = 0; i < 4; ++i) {
      int r = ar + i * 32;
      float4 av = *(const float4*)(A + (size_t)(m0 + r) * D_ + k0 + ac);
      us4 o;
      o[0] = f2bf(av.x); o[1] = f2bf(av.y); o[2] = f2bf(av.z); o[3] = f2bf(av.w);
      *(us4*)(As + r * 32 + ac) = o;
    }
    __syncthreads();
    bf16x8 af[4], bfr[4];
    for (int mi = 0; mi < 4; ++mi)
      af[mi] = *(const bf16x8*)(As + (wr * 64 + mi * 16 + fr) * 32 + fk);
    for (int ni = 0; ni < 4; ++ni)
      bfr[ni] = *(const bf16x8*)(Bs + (wc * 64 + ni * 16 + fr) * 32 + fk);
    for (int mi = 0; mi < 4; ++mi)
      for (int ni = 0; ni < 4; ++ni)
        acc[mi][ni] =
            __builtin_amdgcn_mfma_f32_16x16x32_bf16(af[mi], bfr[ni], acc[mi][ni], 0, 0, 0);
  }

  if (z == 2) {  // Vt [B][H][DH][S]
    for (int mi = 0; mi < 4; ++mi) {
      int rowb = m0 + wr * 64 + mi * 16 + (lane >> 4) * 4;
      int bb2 = rowb >> 11, s0 = rowb & (S_ - 1);
      for (int ni = 0; ni < 4; ++ni) {
        int col = n0 + wc * 64 + ni * 16 + fr;
        int hh = col >> 6, dh = col & 63;
        float bv = bias[col];
        us4 pk;
        for (int r = 0; r < 4; ++r) pk[r] = f2bf(acc[mi][ni][r] + bv);
        *(us4*)(O + ((size_t)(bb2 * H_ + hh) * DH_ + dh) * S_ + s0) = pk;
      }
    }
  } else {       // Qh/Kh [B][H][S][DH]
    float scale = (z == 0) ? 0.125f : 1.0f;
    for (int mi = 0; mi < 4; ++mi) {
      int rowb = m0 + wr * 64 + mi * 16 + (lane >> 4) * 4;
      for (int ni = 0; ni < 4; ++ni) {
        int col = n0 + wc * 64 + ni * 16 + fr;
        int hh = col >> 6, dh = col & 63;
        float bv = bias[col];
        for (int r = 0; r < 4; ++r) {
          int row = rowb + r;
          int bb2 = row >> 11, s = row & (S_ - 1);
          O[((size_t)(bb2 * H_ + hh) * S_ + s) * DH_ + dh] = f2bf((acc[mi][ni][r] + bv) * scale);
        }
      }
    }
  }
}

// ---------------- output GEMM: out fp32 = bf16 A @ Wo^T + bo ----------------
__global__ __launch_bounds__(256) void gemm_out(const u16* __restrict__ A,
                                                const u16* __restrict__ Bt,
                                                const float* __restrict__ bias,
                                                float* __restrict__ O) {
  __shared__ u16 As[128 * 32];
  __shared__ u16 Bs[128 * 32];
  int tid = threadIdx.x;
  int lane = tid & 63, wave = tid >> 6;
  int m0 = blockIdx.x * 128, n0 = blockIdx.y * 128;
  int wr = wave >> 1, wc = wave & 1;
  int fr = lane & 15, fk = (lane >> 4) * 8;

  f32x4 acc[4][4];
  const f32x4 vzero = {0.f, 0.f, 0.f, 0.f};
  for (int i = 0; i < 4; ++i)
    for (int j = 0; j < 4; ++j) acc[i][j] = vzero;

  for (int k0 = 0; k0 < D_; k0 += 32) {
    if (k0) __syncthreads();
    for (int i = 0; i < 2; ++i) {
      int wofs = ((i * 4 + wave) << 10);
      int ofs = wofs + lane * 16;
      int row = ofs >> 6;
      int cole = (ofs & 63) >> 1;
      gload_lds16(A + (size_t)(m0 + row) * D_ + k0 + cole, (char*)As + wofs);
      gload_lds16(Bt + (size_t)(n0 + row) * D_ + k0 + cole, (char*)Bs + wofs);
    }
    __syncthreads();
    bf16x8 af[4], bfr[4];
    for (int mi = 0; mi < 4; ++mi)
      af[mi] = *(const bf16x8*)(As + (wr * 64 + mi * 16 + fr) * 32 + fk);
    for (int ni = 0; ni < 4; ++ni)
      bfr[ni] = *(const bf16x8*)(Bs + (wc * 64 + ni * 16 + fr) * 32 + fk);
    for (int mi = 0; mi < 4; ++mi)
      for (int ni = 0; ni < 4; ++ni)
        acc[mi][ni] =
            __builtin_amdgcn_mfma_f32_16x16x32_bf16(af[mi], bfr[ni], acc[mi][ni], 0, 0, 0);
  }

  for (int mi = 0; mi < 4; ++mi) {
    int rowb = m0 + wr * 64 + mi * 16 + (lane >> 4) * 4;
    for (int ni = 0; ni < 4; ++ni) {
      int col = n0 + wc * 64 + ni * 16 + fr;
      float bv = bias[col];
      for (int r = 0; r < 4; ++r)
        O[(size_t)(rowb + r) * D_ + col] = acc[mi][ni][r] + bv;
    }
  }
}

// ---------------- flash attention v4: 128-key barrier periods ----------------
// grid: 512 blocks, fid -> h = fid&15 (head pinned to XCD fid&7), s = 31-(fid>>4)
// (heavy stripes dispatched first). 512 threads = 8 waves = 2 batches x 4 q-subtiles.
// Per barrier period: 128 keys = 2 sub-tiles of 64 (existing layout/swizzle per sub).
// LDS 128 KB double-buffered => prefetch slack = full period >= HBM latency.
__global__ __launch_bounds__(512) void attn_kernel(const u16* __restrict__ Qh,
                                                   const u16* __restrict__ Kh,
                                                   const u16* __restrict__ Vt,
                                                   const float* __restrict__ relb,
                                                   u16* __restrict__ attnout) {
  __shared__ u16 KVs[2][2][2][2][4096];  // [kind][batch][buf][sub][64x64 bf16] = 128 KB

  int fid = blockIdx.x;
  int h = fid & 15;
  int s = 31 - (fid >> 4);           // heavy stripes first

  int w = threadIdx.x >> 6, lane = threadIdx.x & 63;
  int fr = lane & 15, g = lane >> 4;
  int b = w >> 2, qw = w & 3;
  int q0w = s * 64 + qw * 16;
  int qme = q0w + fr;
  int bh = b * H_ + h;
  int sx = (fr & 7) << 4;            // read-side XOR swizzle (bytes)

  int kind = (w & 3) >> 1, sb = w & 1;
  int i0 = (w >> 2) * 4;
  int srow_lo = lane >> 3;
  int scb = ((lane & 7) * 16);

  const u16* Qb = Qh + ((size_t)bh * S_ + q0w) * DH_;
  bf16x8 qf0 = *(const bf16x8*)(Qb + fr * DH_ + 8 * g);
  bf16x8 qf1 = *(const bf16x8*)(Qb + fr * DH_ + 32 + 8 * g);

  const float* Bq = relb + (size_t)h * S_ * S_ + (size_t)qme * S_ + 4 * g;

  f32x4 acc[4];
  const f32x4 vzero = {0.f, 0.f, 0.f, 0.f};
  for (int f4 = 0; f4 < 4; ++f4) acc[f4] = vzero;
  float m = -1.0e4f, l = 0.f;

  int P = (s + 2) >> 1;              // 128-key periods covering keys <= s*64+63

  auto STAGE = [&](int buf, int kb) {  // stage 128 keys (2 subs) for this wave's plane
    for (int sub = 0; sub < 2; ++sub) {
      for (int i = 0; i < 4; ++i) {
        int ii = i0 + i;
        int row = ii * 8 + srow_lo;
        int cbs = scb ^ ((row & 7) << 4);   // inverse-swizzled source col (involution)
        const u16* src;
        if (kind == 0)
          src = Kh + ((size_t)(sb * H_ + h) * S_ + kb + sub * 64 + row) * DH_ + (cbs >> 1);
        else
          src = Vt + ((size_t)(sb * H_ + h) * DH_ + row) * S_ + kb + sub * 64 + (cbs >> 1);
        gload_lds16(src, &KVs[kind][sb][buf][sub][ii * 512]);
      }
    }
  };

  f32x4 bi[8], bn[8];
  STAGE(0, 0);
  for (int c = 0; c < 8; ++c) bi[c] = *(const f32x4*)(Bq + 16 * c);
  __syncthreads();

  for (int p = 0; p < P; ++p) {
    int kb = p * 128;
    int buf = p & 1;
    if (p + 1 < P) {
      STAGE(buf ^ 1, kb + 128);
      for (int c = 0; c < 8; ++c) bn[c] = *(const f32x4*)(Bq + kb + 128 + 16 * c);
    }

    // swapped QK^T: lane(fr,g) gets scores for q=qme, keys kb+16*idx+4g+r, idx=0..7
    f32x4 sc[8];
    __builtin_amdgcn_s_setprio(1);
    for (int sub = 0; sub < 2; ++sub) {
      const u16* Kt = &KVs[0][b][buf][sub][0];
      for (int c = 0; c < 4; ++c) {
        bf16x8 k0 = *(const bf16x8*)(Kt + (16 * c + fr) * 64 + (((16 * g) ^ sx) >> 1));
        bf16x8 k1 = *(const bf16x8*)(Kt + (16 * c + fr) * 64 + (((64 + 16 * g) ^ sx) >> 1));
        f32x4 z = vzero;
        z = __builtin_amdgcn_mfma_f32_16x16x32_bf16(k0, qf0, z, 0, 0, 0);
        z = __builtin_amdgcn_mfma_f32_16x16x32_bf16(k1, qf1, z, 0, 0, 0);
        sc[sub * 4 + c] = z;
      }
    }
    __builtin_amdgcn_s_setprio(0);
    for (int c = 0; c < 8; ++c)
      for (int r = 0; r < 4; ++r) {
        int key = kb + 16 * c + 4 * g + r;
        sc[c][r] = (key <= qme) ? sc[c][r] + bi[c][r] : -1e30f;
      }
    // row max: 31 in-lane + 2 shfl
    float pm = sc[0][0];
    for (int c = 0; c < 8; ++c)
      for (int r = 0; r < 4; ++r) pm = fmaxf(pm, sc[c][r]);
    pm = fmaxf(pm, __shfl_xor(pm, 16));
    pm = fmaxf(pm, __shfl_xor(pm, 32));
    // defer-max (T13, THR=8)
    if (!__all(pm - m <= 8.0f)) {
      float mn = fmaxf(m, pm);
      float corr = __expf(m - mn);
      m = mn;
      l *= corr;
      float c0 = __shfl(corr, 4 * g + 0);
      float c1 = __shfl(corr, 4 * g + 1);
      float c2 = __shfl(corr, 4 * g + 2);
      float c3 = __shfl(corr, 4 * g + 3);
      for (int f4 = 0; f4 < 4; ++f4) {
        acc[f4][0] *= c0; acc[f4][1] *= c1; acc[f4][2] *= c2; acc[f4][3] *= c3;
      }
    }
    float rs = 0.f;
    for (int c = 0; c < 8; ++c)
      for (int r = 0; r < 4; ++r) {
        sc[c][r] = __expf(sc[c][r] - m);   // exp in place (saves 32 VGPRs)
        rs += sc[c][r];
      }
    rs += __shfl_xor(rs, 16);
    rs += __shfl_xor(rs, 32);
    l += rs;
    union { u16 u[8]; bf16x8 v; } pp[4];
    for (int j = 0; j < 4; ++j)
      for (int r = 0; r < 4; ++r) {
        pp[j].u[r] = f2bf(sc[2 * j][r]);
        pp[j].u[4 + r] = f2bf(sc[2 * j + 1][r]);
      }
    // PV: acc[f4] += sum_j P(16q x 32k_j) @ V(32k_j x 16dh)
    __builtin_amdgcn_s_setprio(1);
    for (int f4 = 0; f4 < 4; ++f4) {
      for (int j = 0; j < 4; ++j) {
        int sub = j >> 1, cc = j & 1;
        const u16* Vl = &KVs[1][b][buf][sub][0];
        union { us4 hh[2]; bf16x8 v; } vf;
        vf.hh[0] = *(const us4*)(Vl + (f4 * 16 + fr) * 64 + (((cc * 64 + 8 * g) ^ sx) >> 1));
        vf.hh[1] = *(const us4*)(Vl + (f4 * 16 + fr) * 64 + (((cc * 64 + 32 + 8 * g) ^ sx) >> 1));
        acc[f4] = __builtin_amdgcn_mfma_f32_16x16x32_bf16(pp[j].v, vf.v, acc[f4], 0, 0, 0);
      }
    }
    __builtin_amdgcn_s_setprio(0);
    for (int c = 0; c < 8; ++c) bi[c] = bn[c];
    __syncthreads();
  }

  float il = 1.f / l;
  for (int r = 0; r < 4; ++r) {
    float ilr = __shfl(il, 4 * g + r);
    int qq = q0w + 4 * g + r;
    u16* ob = attnout + ((size_t)b * S_ + qq) * D_ + h * 64;
    for (int f4 = 0; f4 < 4; ++f4) ob[f4 * 16 + fr] = f2bf(acc[f4][r] * ilr);
  }
}

extern "C" void kernel_launch(void* const* d_in, const int* in_sizes, int n_in,
                              void* d_out, int out_size, void* d_ws, size_t ws_size,
                              hipStream_t stream) {
  const float* q = (const float*)d_in[0];
  const float* k = (const float*)d_in[1];
  const float* v = (const float*)d_in[2];
  const float* rb = (const float*)d_in[4];
  const float* Wq = (const float*)d_in[5];
  const float* bq = (const float*)d_in[6];
  const float* Wk = (const float*)d_in[7];
  const float* bk = (const float*)d_in[8];
  const float* Wv = (const float*)d_in[9];
  const float* bv = (const float*)d_in[10];
  const float* Wo = (const float*)d_in[11];
  const float* bo = (const float*)d_in[12];
  float* out = (float*)d_out;

  char* ws = (char*)d_ws;
  const size_t SZ = (size_t)M_ * D_ * 2;
  u16* Qh = (u16*)(ws);
  u16* Kh = (u16*)(ws + SZ);
  u16* Vt = (u16*)(ws + 2 * SZ);
  u16* Xb = (u16*)(ws + 3 * SZ);          // attn output (bf16 [M][D])
  u16* Wt = (u16*)(ws + 4 * SZ);          // 4 transposed bf16 weights

  wprep_kernel<<<dim3(32, 32, 4), dim3(32, 8), 0, stream>>>(Wq, Wk, Wv, Wo, Wt);

  gemm_qkv<<<dim3(M_ / 128, D_ / 128, 3), 256, 0, stream>>>(q, k, v, Wt, bq, bk, bv,
                                                            Qh, Kh, Vt);

  attn_kernel<<<dim3(512), 512, 0, stream>>>(Qh, Kh, Vt, rb, Xb);

  gemm_out<<<dim3(M_ / 128, D_ / 128), 256, 0, stream>>>(Xb, Wt + 3 * (size_t)D_ * D_,
                                                         bo, out);
}

// Round 6
// 182.585 us; speedup vs baseline: 2.5511x; 1.0452x over previous
//
#include <hip/hip_runtime.h>

typedef unsigned short u16;
typedef __attribute__((ext_vector_type(8))) short bf16x8;
typedef __attribute__((ext_vector_type(4))) float f32x4;
typedef __attribute__((ext_vector_type(4))) unsigned short us4;

#define B_ 2
#define S_ 2048
#define D_ 1024
#define H_ 16
#define DH_ 64
#define M_ 4096 /* B*S */

__device__ __forceinline__ u16 f2bf(float f) {
  unsigned int u = __builtin_bit_cast(unsigned int, f);
  u += 0x7FFFu + ((u >> 16) & 1u);   // RNE
  return (u16)(u >> 16);
}

__device__ __forceinline__ void gload_lds16(const void* g, void* l) {
  __builtin_amdgcn_global_load_lds(
      (__attribute__((address_space(1))) void*)(g),
      (__attribute__((address_space(3))) void*)(l),
      16, 0, 0);
}

// ---------------- weight prep: W[z] [K][N] fp32 -> Wt[z] [N][K] bf16 ----------------
__global__ __launch_bounds__(256) void wprep_kernel(const float* __restrict__ W0,
                                                    const float* __restrict__ W1,
                                                    const float* __restrict__ W2,
                                                    const float* __restrict__ W3,
                                                    u16* __restrict__ Wt) {
  __shared__ float tile[32][33];
  int z = blockIdx.z;
  const float* W = (z == 0) ? W0 : (z == 1) ? W1 : (z == 2) ? W2 : W3;
  u16* out = Wt + (size_t)z * D_ * D_;
  int tx = threadIdx.x, ty = threadIdx.y;
  int x = blockIdx.x * 32 + tx;
  for (int j = 0; j < 32; j += 8)
    tile[ty + j][tx] = W[(size_t)(blockIdx.y * 32 + ty + j) * D_ + x];
  __syncthreads();
  int x2 = blockIdx.y * 32 + tx;
  for (int j = 0; j < 32; j += 8)
    out[(size_t)(blockIdx.x * 32 + ty + j) * D_ + x2] = f2bf(tile[tx][ty + j]);
}

// ---------------- fused QKV GEMM (A fp32 converted during staging) ----------------
__global__ __launch_bounds__(256) void gemm_qkv(const float* __restrict__ qin,
                                                const float* __restrict__ kin,
                                                const float* __restrict__ vin,
                                                const u16* __restrict__ Wt,
                                                const float* __restrict__ bq,
                                                const float* __restrict__ bk,
                                                const float* __restrict__ bv,
                                                u16* __restrict__ Qh,
                                                u16* __restrict__ Kh,
                                                u16* __restrict__ Vt) {
  __shared__ u16 As[128 * 32];
  __shared__ u16 Bs[128 * 32];
  int z = blockIdx.z;
  const float* A = (z == 0) ? qin : (z == 1) ? kin : vin;
  const u16* Bt = Wt + (size_t)z * D_ * D_;
  const float* bias = (z == 0) ? bq : (z == 1) ? bk : bv;
  u16* O = (z == 0) ? Qh : (z == 1) ? Kh : Vt;

  int tid = threadIdx.x;
  int lane = tid & 63, wave = tid >> 6;
  int m0 = blockIdx.x * 128, n0 = blockIdx.y * 128;
  int wr = wave >> 1, wc = wave & 1;
  int fr = lane & 15, fk = (lane >> 4) * 8;
  int ar = tid >> 3, ac = (tid & 7) * 4;

  f32x4 acc[4][4];
  const f32x4 vzero = {0.f, 0.f, 0.f, 0.f};
  for (int i = 0; i < 4; ++i)
    for (int j = 0; j < 4; ++j) acc[i][j] = vzero;

  for (int k0 = 0; k0 < D_; k0 += 32) {
    if (k0) __syncthreads();
    for (int i = 0; i < 2; ++i) {
      int wofs = ((i * 4 + wave) << 10);
      int ofs = wofs + lane * 16;
      int row = ofs >> 6;
      int cole = (ofs & 63) >> 1;
      gload_lds16(Bt + (size_t)(n0 + row) * D_ + k0 + cole, (char*)Bs + wofs);
    }
    for (int i = 0; i < 4; ++i) {
      int r = ar + i * 32;
      float4 av = *(const float4*)(A + (size_t)(m0 + r) * D_ + k0 + ac);
      us4 o;
      o[0] = f2bf(av.x); o[1] = f2bf(av.y); o[2] = f2bf(av.z); o[3] = f2bf(av.w);
      *(us4*)(As + r * 32 + ac) = o;
    }
    __syncthreads();
    bf16x8 af[4], bfr[4];
    for (int mi = 0; mi < 4; ++mi)
      af[mi] = *(const bf16x8*)(As + (wr * 64 + mi * 16 + fr) * 32 + fk);
    for (int ni = 0; ni < 4; ++ni)
      bfr[ni] = *(const bf16x8*)(Bs + (wc * 64 + ni * 16 + fr) * 32 + fk);
    for (int mi = 0; mi < 4; ++mi)
      for (int ni = 0; ni < 4; ++ni)
        acc[mi][ni] =
            __builtin_amdgcn_mfma_f32_16x16x32_bf16(af[mi], bfr[ni], acc[mi][ni], 0, 0, 0);
  }

  if (z == 2) {  // Vt [B][H][DH][S]
    for (int mi = 0; mi < 4; ++mi) {
      int rowb = m0 + wr * 64 + mi * 16 + (lane >> 4) * 4;
      int bb2 = rowb >> 11, s0 = rowb & (S_ - 1);
      for (int ni = 0; ni < 4; ++ni) {
        int col = n0 + wc * 64 + ni * 16 + fr;
        int hh = col >> 6, dh = col & 63;
        float bv = bias[col];
        us4 pk;
        for (int r = 0; r < 4; ++r) pk[r] = f2bf(acc[mi][ni][r] + bv);
        *(us4*)(O + ((size_t)(bb2 * H_ + hh) * DH_ + dh) * S_ + s0) = pk;
      }
    }
  } else {       // Qh/Kh [B][H][S][DH]
    float scale = (z == 0) ? 0.125f : 1.0f;
    for (int mi = 0; mi < 4; ++mi) {
      int rowb = m0 + wr * 64 + mi * 16 + (lane >> 4) * 4;
      for (int ni = 0; ni < 4; ++ni) {
        int col = n0 + wc * 64 + ni * 16 + fr;
        int hh = col >> 6, dh = col & 63;
        float bv = bias[col];
        for (int r = 0; r < 4; ++r) {
          int row = rowb + r;
          int bb2 = row >> 11, s = row & (S_ - 1);
          O[((size_t)(bb2 * H_ + hh) * S_ + s) * DH_ + dh] = f2bf((acc[mi][ni][r] + bv) * scale);
        }
      }
    }
  }
}

// ---------------- output GEMM: out fp32 = bf16 A @ Wo^T + bo ----------------
__global__ __launch_bounds__(256) void gemm_out(const u16* __restrict__ A,
                                                const u16* __restrict__ Bt,
                                                const float* __restrict__ bias,
                                                float* __restrict__ O) {
  __shared__ u16 As[128 * 32];
  __shared__ u16 Bs[128 * 32];
  int tid = threadIdx.x;
  int lane = tid & 63, wave = tid >> 6;
  int m0 = blockIdx.x * 128, n0 = blockIdx.y * 128;
  int wr = wave >> 1, wc = wave & 1;
  int fr = lane & 15, fk = (lane >> 4) * 8;

  f32x4 acc[4][4];
  const f32x4 vzero = {0.f, 0.f, 0.f, 0.f};
  for (int i = 0; i < 4; ++i)
    for (int j = 0; j < 4; ++j) acc[i][j] = vzero;

  for (int k0 = 0; k0 < D_; k0 += 32) {
    if (k0) __syncthreads();
    for (int i = 0; i < 2; ++i) {
      int wofs = ((i * 4 + wave) << 10);
      int ofs = wofs + lane * 16;
      int row = ofs >> 6;
      int cole = (ofs & 63) >> 1;
      gload_lds16(A + (size_t)(m0 + row) * D_ + k0 + cole, (char*)As + wofs);
      gload_lds16(Bt + (size_t)(n0 + row) * D_ + k0 + cole, (char*)Bs + wofs);
    }
    __syncthreads();
    bf16x8 af[4], bfr[4];
    for (int mi = 0; mi < 4; ++mi)
      af[mi] = *(const bf16x8*)(As + (wr * 64 + mi * 16 + fr) * 32 + fk);
    for (int ni = 0; ni < 4; ++ni)
      bfr[ni] = *(const bf16x8*)(Bs + (wc * 64 + ni * 16 + fr) * 32 + fk);
    for (int mi = 0; mi < 4; ++mi)
      for (int ni = 0; ni < 4; ++ni)
        acc[mi][ni] =
            __builtin_amdgcn_mfma_f32_16x16x32_bf16(af[mi], bfr[ni], acc[mi][ni], 0, 0, 0);
  }

  for (int mi = 0; mi < 4; ++mi) {
    int rowb = m0 + wr * 64 + mi * 16 + (lane >> 4) * 4;
    for (int ni = 0; ni < 4; ++ni) {
      int col = n0 + wc * 64 + ni * 16 + fr;
      float bv = bias[col];
      for (int r = 0; r < 4; ++r)
        O[(size_t)(rowb + r) * D_ + col] = acc[mi][ni][r] + bv;
    }
  }
}

// ---------------- flash attention v5: occupancy-first ----------------
// 1024 blocks x 256 threads (4 waves x 16 q-rows = 64-row stripe), batch in grid.
// fid -> b=(fid>>3)&1, rest=(fid>>4)*8+(fid&7), h=rest&15, s=31-(rest>>4):
// b=0/b=1 copies of (h,s) are fid and fid+8 -> same XCD -> bias shared via L2;
// head pinned to XCD (K/V L2-resident); heavy stripes first.
// LDS 32 KB (K+V 64-key tile, double-buffered) -> target 4 blocks/CU, 16 waves/CU.
__global__ __launch_bounds__(256, 4) void attn_kernel(const u16* __restrict__ Qh,
                                                      const u16* __restrict__ Kh,
                                                      const u16* __restrict__ Vt,
                                                      const float* __restrict__ relb,
                                                      u16* __restrict__ attnout) {
  __shared__ u16 KVs[2][2][4096];  // [kind][buf][64x64 bf16] = 32 KB

  int fid = blockIdx.x;
  int b = (fid >> 3) & 1;
  int rest = (fid >> 4) * 8 + (fid & 7);
  int h = rest & 15;
  int s = 31 - (rest >> 4);          // heavy stripes first

  int w = threadIdx.x >> 6, lane = threadIdx.x & 63;
  int fr = lane & 15, g = lane >> 4;
  int q0w = s * 64 + w * 16;
  int qme = q0w + fr;
  int bh = b * H_ + h;
  int sx = (fr & 7) << 4;            // read-side XOR swizzle (bytes)

  // staging duty: kind = w>>1 (0=K,1=V), half i0 = (w&1)*4
  int kind = w >> 1;
  int i0 = (w & 1) * 4;
  int srow_lo = lane >> 3;
  int scb = (lane & 7) * 16;

  const u16* Qb = Qh + ((size_t)bh * S_ + q0w) * DH_;
  bf16x8 qf0 = *(const bf16x8*)(Qb + fr * DH_ + 8 * g);
  bf16x8 qf1 = *(const bf16x8*)(Qb + fr * DH_ + 32 + 8 * g);

  const float* Bq = relb + (size_t)h * S_ * S_ + (size_t)qme * S_ + 4 * g;

  f32x4 acc[4];
  const f32x4 vzero = {0.f, 0.f, 0.f, 0.f};
  for (int f4 = 0; f4 < 4; ++f4) acc[f4] = vzero;
  float m = -1.0e4f, l = 0.f;

  int T = s + 1;                     // 64-key tiles covering keys <= s*64+63

  auto STAGE = [&](int buf, int kb) {  // this wave stages half of its plane (4 KB)
    for (int i = 0; i < 4; ++i) {
      int ii = i0 + i;
      int row = ii * 8 + srow_lo;
      int cbs = scb ^ ((row & 7) << 4);   // inverse-swizzled source col (involution)
      const u16* src;
      if (kind == 0)
        src = Kh + ((size_t)bh * S_ + kb + row) * DH_ + (cbs >> 1);
      else
        src = Vt + ((size_t)bh * DH_ + row) * S_ + kb + (cbs >> 1);
      gload_lds16(src, &KVs[kind][buf][ii * 512]);
    }
  };

  STAGE(0, 0);
  __syncthreads();

  for (int t = 0; t < T; ++t) {
    int kb = t * 64;
    int buf = t & 1;
    if (t + 1 < T) STAGE(buf ^ 1, kb + 64);
    // bias for current tile (per-lane registers; latency covered by cross-block TLP)
    f32x4 bi[4];
    for (int c = 0; c < 4; ++c) bi[c] = *(const f32x4*)(Bq + kb + 16 * c);

    const u16* Kt = &KVs[0][buf][0];
    const u16* Vl = &KVs[1][buf][0];

    // swapped QK^T: lane(fr,g) gets scores for q=qme, keys kb+16c+4g+r
    f32x4 sc[4];
    __builtin_amdgcn_s_setprio(1);
    for (int c = 0; c < 4; ++c) {
      bf16x8 k0 = *(const bf16x8*)(Kt + (16 * c + fr) * 64 + (((16 * g) ^ sx) >> 1));
      bf16x8 k1 = *(const bf16x8*)(Kt + (16 * c + fr) * 64 + (((64 + 16 * g) ^ sx) >> 1));
      f32x4 z = vzero;
      z = __builtin_amdgcn_mfma_f32_16x16x32_bf16(k0, qf0, z, 0, 0, 0);
      z = __builtin_amdgcn_mfma_f32_16x16x32_bf16(k1, qf1, z, 0, 0, 0);
      sc[c] = z;
    }
    __builtin_amdgcn_s_setprio(0);
    for (int c = 0; c < 4; ++c)
      for (int r = 0; r < 4; ++r) {
        int key = kb + 16 * c + 4 * g + r;
        sc[c][r] = (key <= qme) ? sc[c][r] + bi[c][r] : -1e30f;
      }
    // row max: 15 in-lane + 2 shfl (lanes fr,fr+16,fr+32,fr+48 share q)
    float pm = sc[0][0];
    for (int c = 0; c < 4; ++c)
      for (int r = 0; r < 4; ++r) pm = fmaxf(pm, sc[c][r]);
    pm = fmaxf(pm, __shfl_xor(pm, 16));
    pm = fmaxf(pm, __shfl_xor(pm, 32));
    // defer-max (T13, THR=8)
    if (!__all(pm - m <= 8.0f)) {
      float mn = fmaxf(m, pm);
      float corr = __expf(m - mn);
      m = mn;
      l *= corr;
      float c0 = __shfl(corr, 4 * g + 0);
      float c1 = __shfl(corr, 4 * g + 1);
      float c2 = __shfl(corr, 4 * g + 2);
      float c3 = __shfl(corr, 4 * g + 3);
      for (int f4 = 0; f4 < 4; ++f4) {
        acc[f4][0] *= c0; acc[f4][1] *= c1; acc[f4][2] *= c2; acc[f4][3] *= c3;
      }
    }
    float rs = 0.f;
    for (int c = 0; c < 4; ++c)
      for (int r = 0; r < 4; ++r) {
        sc[c][r] = __expf(sc[c][r] - m);   // exp in place
        rs += sc[c][r];
      }
    rs += __shfl_xor(rs, 16);
    rs += __shfl_xor(rs, 32);
    l += rs;
    union { u16 u[8]; bf16x8 v; } pp[2];
    for (int j = 0; j < 2; ++j)
      for (int r = 0; r < 4; ++r) {
        pp[j].u[r] = f2bf(sc[2 * j][r]);
        pp[j].u[4 + r] = f2bf(sc[2 * j + 1][r]);
      }
    // PV: acc[f4] += sum_j P(16q x 32k_j) @ V(32k_j x 16dh)
    __builtin_amdgcn_s_setprio(1);
    for (int f4 = 0; f4 < 4; ++f4) {
      for (int j = 0; j < 2; ++j) {
        union { us4 hh[2]; bf16x8 v; } vf;
        vf.hh[0] = *(const us4*)(Vl + (f4 * 16 + fr) * 64 + (((j * 64 + 8 * g) ^ sx) >> 1));
        vf.hh[1] = *(const us4*)(Vl + (f4 * 16 + fr) * 64 + (((j * 64 + 32 + 8 * g) ^ sx) >> 1));
        acc[f4] = __builtin_amdgcn_mfma_f32_16x16x32_bf16(pp[j].v, vf.v, acc[f4], 0, 0, 0);
      }
    }
    __builtin_amdgcn_s_setprio(0);
    __syncthreads();
  }

  float il = 1.f / l;
  for (int r = 0; r < 4; ++r) {
    float ilr = __shfl(il, 4 * g + r);
    int qq = q0w + 4 * g + r;
    u16* ob = attnout + ((size_t)b * S_ + qq) * D_ + h * 64;
    for (int f4 = 0; f4 < 4; ++f4) ob[f4 * 16 + fr] = f2bf(acc[f4][r] * ilr);
  }
}

extern "C" void kernel_launch(void* const* d_in, const int* in_sizes, int n_in,
                              void* d_out, int out_size, void* d_ws, size_t ws_size,
                              hipStream_t stream) {
  const float* q = (const float*)d_in[0];
  const float* k = (const float*)d_in[1];
  const float* v = (const float*)d_in[2];
  const float* rb = (const float*)d_in[4];
  const float* Wq = (const float*)d_in[5];
  const float* bq = (const float*)d_in[6];
  const float* Wk = (const float*)d_in[7];
  const float* bk = (const float*)d_in[8];
  const float* Wv = (const float*)d_in[9];
  const float* bv = (const float*)d_in[10];
  const float* Wo = (const float*)d_in[11];
  const float* bo = (const float*)d_in[12];
  float* out = (float*)d_out;

  char* ws = (char*)d_ws;
  const size_t SZ = (size_t)M_ * D_ * 2;
  u16* Qh = (u16*)(ws);
  u16* Kh = (u16*)(ws + SZ);
  u16* Vt = (u16*)(ws + 2 * SZ);
  u16* Xb = (u16*)(ws + 3 * SZ);          // attn output (bf16 [M][D])
  u16* Wt = (u16*)(ws + 4 * SZ);          // 4 transposed bf16 weights

  wprep_kernel<<<dim3(32, 32, 4), dim3(32, 8), 0, stream>>>(Wq, Wk, Wv, Wo, Wt);

  gemm_qkv<<<dim3(M_ / 128, D_ / 128, 3), 256, 0, stream>>>(q, k, v, Wt, bq, bk, bv,
                                                            Qh, Kh, Vt);

  attn_kernel<<<dim3(1024), 256, 0, stream>>>(Qh, Kh, Vt, rb, Xb);

  gemm_out<<<dim3(M_ / 128, D_ / 128), 256, 0, stream>>>(Xb, Wt + 3 * (size_t)D_ * D_,
                                                         bo, out);
}